// Round 18
// baseline (843.159 us; speedup 1.0000x reference)
//
#include <hip/hip_runtime.h>

// ---------------------------------------------------------------------------
// Decoder: out = (tanh(x @ (s1*tern(w1-n1)) + b1)) @ (s2*tern(w2-n2)) + b2
// B=4096, D_IN=1024, D_H=16384, D_OUT=3072
//
// Round-20: single change vs round-17 (best, 831.6us): the three independent
// pack/quant kernels fused into ONE dispatch (prep_kernel, 11264 blocks x
// 256 thr, flat block-id partition: [0,6144) w2-i8 | [6144,10240) w1-bf16 |
// [10240,11264) pack_x). Bodies byte-identical; intra-section block order
// matches the old x-fastest grids. Removes two full pipeline-drain
// boundaries and forces the packer stage to surface in the top-5 with
// counters (it was always hidden below the slowest-kernel floor).
// gemm1 / gemm2 byte-identical to round-17.
//
// bf16 chunk (8192 B = 128(m|n) x 32(k)): elem offs = s*1024+h*512+lane*8+e
// i8  chunk (4096 B = 128(m|n) x 32(k)): byte = s*1024 + lane*16 + e,
//   elem = T[s*32+(lane&31)][(lane>>5)*16+e]
// ---------------------------------------------------------------------------

typedef __bf16 bf16x8 __attribute__((ext_vector_type(8)));
typedef float f32x16 __attribute__((ext_vector_type(16)));
typedef int i32x4 __attribute__((ext_vector_type(4)));
typedef int i32x16 __attribute__((ext_vector_type(16)));

#define AS1 __attribute__((address_space(1)))
#define AS3 __attribute__((address_space(3)))

__device__ __forceinline__ void gload_lds16(const void* g, void* l) {
    __builtin_amdgcn_global_load_lds((AS1 const void*)g, (AS3 void*)l, 16, 0, 0);
}

__device__ __forceinline__ unsigned short f2bf(float f) {
    union { float f; unsigned int u; } v; v.f = f;
    unsigned int u = v.u;
    unsigned int r = u + 0x7fffu + ((u >> 16) & 1u);
    return (unsigned short)(r >> 16);
}

__device__ __forceinline__ unsigned short tern_bf(float q) {
    return (q > 1.f) ? 0x3F80u : ((q < -1.f) ? 0xBF80u : 0u);
}

__device__ __forceinline__ float load_scale(const void* p) {
    int i = *(const int*)p;
    if (i >= -1000000 && i <= 1000000) return (float)i;
    union { int i; float f; } v; v.i = i; return v.f;
}

__device__ __forceinline__ float tanh_fast(float x) {
    float e = __expf(2.0f * x);
    return 1.0f - 2.0f * __builtin_amdgcn_rcpf(e + 1.0f);
}

// ---------------------------------------------------------------------------
// prep_kernel: fused pack_x (bf16) + quant_w1 (bf16) + quant_w2 (i8).
// Flat 1-D grid, 256 thr. Sections (longest first):
//   [0, 6144):        w2 i8 quant  (nt = r%24, ktp = r/24)
//   [6144, 10240):    w1 bf16 quant (nt = r%128, kt = r/128)
//   [10240, 11264):   pack_x       (kt = r%32, mt = r/32)
// ---------------------------------------------------------------------------
__global__ __launch_bounds__(256) void prep_kernel(
    const float* __restrict__ x,  unsigned short* __restrict__ xq,
    const float* __restrict__ w1, const float* __restrict__ n1,
    unsigned short* __restrict__ w1q,
    const float* __restrict__ w2, const float* __restrict__ n2,
    unsigned char* __restrict__ w2q,
    const void* __restrict__ scale_ptr)
{
    __shared__ unsigned short lt[128 * 34];      // used by the w1 branch only
    const int bid = blockIdx.x, tid = threadIdx.x;

    if (bid < 6144) {
        // ---- quant_w2 -> i8 chunks [nt=24][k2c=512][4096B] ----
        const int r = bid;
        const int nt = r % 24, ktp = r / 24;
        const int c = tid >> 7, rr = tid & 127, ng = rr & 31, kg = rr >> 5;
        const int kt = ktp * 2 + c;
        const float scale = load_scale(scale_ptr);
        const int k0 = kt * 32 + kg * 8;
        const int n0 = nt * 128 + ng * 4;

        int us[8][4];
#pragma unroll
        for (int i = 0; i < 8; i++) {
            size_t g = (size_t)(k0 + i) * 3072 + n0;
            float4 wv = *(const float4*)(w2 + g);
            float4 nv = *(const float4*)(n2 + g);
            float q0 = wv.x - scale * nv.x, q1 = wv.y - scale * nv.y;
            float q2 = wv.z - scale * nv.z, q3 = wv.w - scale * nv.w;
            us[i][0] = (q0 > 1.f) - (q0 < -1.f);
            us[i][1] = (q1 > 1.f) - (q1 < -1.f);
            us[i][2] = (q2 > 1.f) - (q2 < -1.f);
            us[i][3] = (q3 > 1.f) - (q3 < -1.f);
        }

        unsigned char* chunk = w2q + (size_t)(nt * 512 + kt) * 4096;
        const int hi = kg >> 1, eb = (kg & 1) * 8;
#pragma unroll
        for (int j = 0; j < 4; j++) {
            int nl = ng * 4 + j;
            int addr = (nl >> 5) * 1024 + (hi * 32 + (nl & 31)) * 16 + eb;
            unsigned int lo = (us[0][j] & 255) | ((us[1][j] & 255) << 8)
                            | ((us[2][j] & 255) << 16) | ((us[3][j] & 255) << 24);
            unsigned int hw = (us[4][j] & 255) | ((us[5][j] & 255) << 8)
                            | ((us[6][j] & 255) << 16) | ((us[7][j] & 255) << 24);
            uint2 o; o.x = lo; o.y = hw;
            *(uint2*)&chunk[addr] = o;
        }
    } else if (bid < 10240) {
        // ---- quant_w1 -> bf16 chunks [nt=128][kt=32][8192B] ----
        const int r = bid - 6144;
        const int nt = r % 128, kt = r / 128;
        const float scale = load_scale(scale_ptr);
#pragma unroll
        for (int it = 0; it < 4; it++) {
            int p = it * 1024 + tid * 4;
            int kr = p >> 7, nc = p & 127;
            size_t g = (size_t)(kt * 32 + kr) * 16384 + nt * 128 + nc;
            float4 wv = *(const float4*)(w1 + g);
            float4 nv = *(const float4*)(n1 + g);
            lt[(nc + 0) * 34 + kr] = tern_bf(wv.x - scale * nv.x);
            lt[(nc + 1) * 34 + kr] = tern_bf(wv.y - scale * nv.y);
            lt[(nc + 2) * 34 + kr] = tern_bf(wv.z - scale * nv.z);
            lt[(nc + 3) * 34 + kr] = tern_bf(wv.w - scale * nv.w);
        }
        __syncthreads();
        unsigned short* chunk = w1q + (size_t)(nt * 32 + kt) * 4096;
#pragma unroll
        for (int it = 0; it < 2; it++) {
            int g = tid + it * 256;
            int s = g >> 7, rr = g & 127, h = (rr >> 6) & 1, ln = rr & 63;
            int n = s * 32 + (ln & 31), k = h * 16 + (ln >> 5) * 8;
            const unsigned int* p32 = (const unsigned int*)&lt[n * 34 + k];
            uint4 o; o.x = p32[0]; o.y = p32[1]; o.z = p32[2]; o.w = p32[3];
            *(uint4*)&chunk[(size_t)g * 8] = o;
        }
    } else {
        // ---- pack_x -> bf16 chunks [mt=32][kt=32][8192B] ----
        const int r = bid - 10240;
        const int kt = r % 32, mt = r / 32;
        unsigned short* chunk = xq + (size_t)(mt * 32 + kt) * 4096;
#pragma unroll
        for (int it = 0; it < 2; it++) {
            int g = tid + it * 256;
            int s = g >> 7, rr = g & 127, h = (rr >> 6) & 1, ln = rr & 63;
            int m = s * 32 + (ln & 31), k = h * 16 + (ln >> 5) * 8;
            const float* src = x + (size_t)(mt * 128 + m) * 1024 + kt * 32 + k;
            float4 v0 = *(const float4*)src;
            float4 v1 = *(const float4*)(src + 4);
            unsigned int w0 = (unsigned int)f2bf(v0.x) | ((unsigned int)f2bf(v0.y) << 16);
            unsigned int w1v = (unsigned int)f2bf(v0.z) | ((unsigned int)f2bf(v0.w) << 16);
            unsigned int w2v = (unsigned int)f2bf(v1.x) | ((unsigned int)f2bf(v1.y) << 16);
            unsigned int w3 = (unsigned int)f2bf(v1.z) | ((unsigned int)f2bf(v1.w) << 16);
            uint4 o; o.x = w0; o.y = w1v; o.z = w2v; o.w = w3;
            *(uint4*)&chunk[(size_t)g * 8] = o;
        }
    }
}

// ---------------------------------------------------------------------------
// Shared sync macros
// ---------------------------------------------------------------------------
#define VMCNT(n) asm volatile("s_waitcnt vmcnt(" #n ")" ::: "memory")
#define BARRIER() { asm volatile("" ::: "memory"); __builtin_amdgcn_s_barrier(); asm volatile("" ::: "memory"); }
#define NOWAIT ((void)0)

// ---- 256^2 bf16 template pieces (gemm1 core, round-13 verified) -----------
#define RD_FRAG(dst, HALF, SUB, P)                                            \
    dst[0] = *(const bf16x8*)&lds[P][HALF][(SUB)*1024 + lane*8];              \
    dst[1] = *(const bf16x8*)&lds[P][HALF][(SUB)*1024 + 512 + lane*8];        \
    dst[2] = *(const bf16x8*)&lds[P][HALF][4096 + (SUB)*1024 + lane*8];       \
    dst[3] = *(const bf16x8*)&lds[P][HALF][4096 + (SUB)*1024 + 512 + lane*8];

#define MFMA4(ci, cj, av, bv)                                                 \
    acc[ci][cj] = __builtin_amdgcn_mfma_f32_32x32x16_bf16(av[0], bv[0], acc[ci][cj], 0,0,0); \
    acc[ci][cj] = __builtin_amdgcn_mfma_f32_32x32x16_bf16(av[1], bv[1], acc[ci][cj], 0,0,0); \
    acc[ci][cj] = __builtin_amdgcn_mfma_f32_32x32x16_bf16(av[2], bv[2], acc[ci][cj], 0,0,0); \
    acc[ci][cj] = __builtin_amdgcn_mfma_f32_32x32x16_bf16(av[3], bv[3], acc[ci][cj], 0,0,0);

#define GSTEP(P, Q, T, WA, WB, WC, DO_STAGE)                                  \
  { if (DO_STAGE) STAGE(Q, 0, (T) + 1);                                       \
    WA; BARRIER();                                                            \
    RD_FRAG(fa0, 0, sA, P); RD_FRAG(fa1, 0, sA + 1, P);                       \
    RD_FRAG(fb0, 2, sB, P); RD_FRAG(fb1, 3, sB, P);                           \
    __builtin_amdgcn_s_setprio(1);                                            \
    MFMA4(0, 0, fa0, fb0); MFMA4(1, 0, fa1, fb0);                             \
    __builtin_amdgcn_s_setprio(0);                                            \
    if (DO_STAGE) STAGE(Q, 2, (T) + 1);                                       \
    WB;                                                                       \
    __builtin_amdgcn_s_setprio(1);                                            \
    MFMA4(0, 1, fa0, fb1); MFMA4(1, 1, fa1, fb1);                             \
    __builtin_amdgcn_s_setprio(0);                                            \
    if (DO_STAGE) STAGE(Q, 3, (T) + 1);                                       \
    BARRIER();                                                                \
    RD_FRAG(fa0, 1, sA, P); RD_FRAG(fa1, 1, sA + 1, P);                       \
    __builtin_amdgcn_s_setprio(1);                                            \
    MFMA4(2, 1, fa0, fb1); MFMA4(3, 1, fa1, fb1);                             \
    __builtin_amdgcn_s_setprio(0);                                            \
    if (DO_STAGE) STAGE(Q, 1, (T) + 1);                                       \
    WC;                                                                       \
    __builtin_amdgcn_s_setprio(1);                                            \
    MFMA4(2, 0, fa0, fb0); MFMA4(3, 0, fa1, fb0);                             \
    __builtin_amdgcn_s_setprio(0);                                            \
  }

// ---------------------------------------------------------------------------
// GEMM1 (256^2, swapped, bf16 core; round-13 verified): A = w1q, B = xq.
// acc = h^T: k2 over regs, m over lanes. Epilogue emits i8 hq (round-17
// verified): q = rint(127*tanh), 64 KB LDS chunk image, coalesced stream.
// Grid 16x64 = 1024 blocks; XCD-chunked swizzle.
// ---------------------------------------------------------------------------
__global__ __launch_bounds__(512, 2) void gemm1_256_kernel(
    const unsigned short* __restrict__ Ap,   // w1q chunks [(n1>>7)][kt=32]
    const unsigned short* __restrict__ Bp,   // xq  chunks [(m>>7)][kt=32]
    unsigned char* __restrict__ Hq,          // i8 chunks [m128][k2c=512] 4KB
    const float* __restrict__ s1v, const float* __restrict__ b1v)
{
    __shared__ unsigned short lds[2][4][8192];   // 128 KiB
    const int tid = threadIdx.x;
    const int lane = tid & 63, wave = tid >> 6;
    const int bid0 = blockIdx.x + 16 * blockIdx.y;
    const int wg = (bid0 & 7) * 128 + (bid0 >> 3);
    const int NT = wg & 15;        // batch / 256
    const int MT = wg >> 4;        // n1 / 256
    const int wm = ((wave >> 2) & 1) * 64;
    const int sA = wm >> 5;
    const int sB = wave & 3;

    f32x16 acc[4][2] = {};

    const unsigned short* Ab = Ap + ((size_t)(2 * MT) * 32) * 4096;
    const unsigned short* Bb = Bp + ((size_t)(2 * NT) * 32) * 4096;

    auto STAGE = [&](int q, int half, int t) {
        const unsigned short* g = (half < 2)
            ? (Ab + ((size_t)(half * 32 + 2 * t)) * 4096)
            : (Bb + ((size_t)((half - 2) * 32 + 2 * t)) * 4096);
        unsigned short* l = &lds[q][half][0];
        gload_lds16(g + tid * 8,        l + tid * 8);
        gload_lds16(g + 4096 + tid * 8, l + 4096 + tid * 8);
    };

    bf16x8 fa0[4], fa1[4], fb0[4], fb1[4];

    STAGE(0, 0, 0); STAGE(0, 2, 0); STAGE(0, 3, 0); STAGE(0, 1, 0);

    for (int t = 0; t < 14; t += 2) {
        GSTEP(0, 1, t,     VMCNT(4), VMCNT(4), VMCNT(4), true);
        GSTEP(1, 0, t + 1, VMCNT(4), VMCNT(4), VMCNT(4), true);
    }
    GSTEP(0, 1, 14, VMCNT(4), VMCNT(4), VMCNT(4), true);
    GSTEP(1, 0, 15, VMCNT(2), VMCNT(0), NOWAIT,  false);

    __syncthreads();

    // ---- epilogue: q = rint(127*tanh(s1*acc+b1)) -> i8 chunk image (64 KB)
    const int mloc = lane & 31, hi = lane >> 5;
    unsigned int* stg32 = (unsigned int*)&lds[0][0][0];
#pragma unroll
    for (int i = 0; i < 4; i++) {
        const int kc  = (i >> 1) * 4 + sA + (i & 1);   // 0..7, disjoint per wm
        const int k2b = MT * 256 + (i >> 1) * 128 + wm + (i & 1) * 32;
#pragma unroll
        for (int j = 0; j < 2; j++) {
#pragma unroll
            for (int g = 0; g < 4; g++) {
                unsigned int pw = 0;
#pragma unroll
                for (int rr = 0; rr < 4; rr++) {
                    const int n1g = k2b + rr + 8 * g + 4 * hi;
                    float t = tanh_fast(s1v[n1g] * acc[i][j][4 * g + rr] + b1v[n1g]);
                    int q = __float2int_rn(t * 127.0f);
                    pw |= ((unsigned int)(q & 255)) << (8 * rr);
                }
                const int w32 = (j * 8 + kc) * 1024 + sB * 256 + (g >> 1) * 128
                              + mloc * 4 + (g & 1) * 2 + hi;
                stg32[w32] = pw;
            }
        }
    }
    __syncthreads();

    // stream out: per m-group, 8 contiguous 4KB chunks = 32 KB = 2048 uint4
#pragma unroll
    for (int mg = 0; mg < 2; mg++) {
        uint4* dst = (uint4*)(Hq + ((size_t)((2 * NT + mg) * 512 + MT * 8)) * 4096);
        const uint4* src = (const uint4*)&lds[0][0][0];
#pragma unroll
        for (int it = 0; it < 4; it++)
            dst[it * 512 + tid] = src[mg * 2048 + it * 512 + tid];
    }
}

// ---------------------------------------------------------------------------
// GEMM2 (256x192, i8; round-17 verified): out = s2[n]*acc_i32/127 + b2[n].
// Grid 16x16 = 256 blocks (exact fill); XCD swizzle. 8 waves = 4M x 2N;
// wave tile 64 x 96 = acc[2][3] (i32x16). LDS 56 KB.
// ---------------------------------------------------------------------------
__global__ __launch_bounds__(512, 2) void gemm2_192_i8(
    const unsigned char* __restrict__ Ap,   // hq  i8 chunks [m128][k2c=512]
    const unsigned char* __restrict__ Bp,   // w2q i8 chunks [n128][k2c=512]
    float* __restrict__ out,
    const float* __restrict__ s2, const float* __restrict__ b2)
{
    __shared__ unsigned char lds[2][28672];  // A [0,16384) B [16384,28672)
    const int tid = threadIdx.x;
    const int lane = tid & 63, wave = tid >> 6;
    const int bid0 = blockIdx.x + 16 * blockIdx.y;
    const int wg = (bid0 & 7) * 32 + (bid0 >> 3);
    const int NT = wg & 15;                  // D_OUT/192
    const int MT = wg >> 4;                  // B/256
    const int wM = wave >> 1, wN = wave & 1;

    i32x16 acc[2][3] = {};

    const unsigned char* Abase = Ap + ((size_t)(2 * MT) * 512) * 4096;
    const int ar = tid >> 8, aw = (tid & 255) * 16;

    auto boff = [&](int f) -> size_t {
        int kc = (f >= 384);
        int rem = f * 16 - kc * 6144;
        int u = rem >> 11, wi = rem & 2047;
        int uab = 3 * NT + u;
        return ((size_t)((uab >> 1) * 512 + kc)) * 4096 + (uab & 1) * 2048 + wi;
    };
    const size_t b0o = boff(tid);
    const size_t b1o = boff(512 + (tid & 255));
    const int b0d = 16384 + tid * 16;
    const int b1d = 16384 + (512 + (tid & 255)) * 16;

    auto STAGE_A = [&](int q, int kc, int t) {
        gload_lds16(Abase + ((size_t)(ar * 512 + kc)) * 4096 + aw + (size_t)t * 8192,
                    &lds[q][kc * 8192 + ar * 4096 + aw]);
    };
    auto STAGE_B0 = [&](int q, int t) {
        gload_lds16(Bp + b0o + (size_t)t * 8192, &lds[q][b0d]);
    };
    auto STAGE_B1 = [&](int q, int t) {
        gload_lds16(Bp + b1o + (size_t)t * 8192, &lds[q][b1d]);
    };

    i32x4 fa[2], fb[3];
#define RDA8(i, kc, P) {                                                       \
    int sub = 2 * wM + (i);                                                    \
    fa[i] = *(const i32x4*)&lds[P][(kc) * 8192 + (sub >> 2) * 4096             \
                                   + (sub & 3) * 1024 + lane * 16]; }
#define RDB8(j, kc, P)                                                         \
    fb[j] = *(const i32x4*)&lds[P][16384 + (kc) * 6144 + (3 * wN + (j)) * 1024 \
                                   + lane * 16];
#define MFMA8(ci, cj)                                                          \
    acc[ci][cj] = __builtin_amdgcn_mfma_i32_32x32x32_i8(fa[ci], fb[cj], acc[ci][cj], 0, 0, 0);

#define GS8(P, Q, T, W1, W3, DO_STAGE)                                         \
  { if (DO_STAGE) STAGE_A(Q, 0, (T) + 1);                                      \
    W1; BARRIER();                                                             \
    RDA8(0, 0, P); RDA8(1, 0, P);                                              \
    RDB8(0, 0, P); RDB8(1, 0, P); RDB8(2, 0, P);                               \
    __builtin_amdgcn_s_setprio(1);                                             \
    MFMA8(0, 0); MFMA8(0, 1); MFMA8(0, 2);                                     \
    __builtin_amdgcn_s_setprio(0);                                             \
    if (DO_STAGE) STAGE_B0(Q, (T) + 1);                                        \
    __builtin_amdgcn_s_setprio(1);                                             \
    MFMA8(1, 0); MFMA8(1, 1); MFMA8(1, 2);                                     \
    __builtin_amdgcn_s_setprio(0);                                             \
    if (DO_STAGE) STAGE_A(Q, 1, (T) + 1);                                      \
    W3; BARRIER();                                                             \
    RDA8(0, 1, P); RDA8(1, 1, P);                                              \
    RDB8(0, 1, P); RDB8(1, 1, P); RDB8(2, 1, P);                               \
    __builtin_amdgcn_s_setprio(1);                                             \
    MFMA8(0, 0); MFMA8(0, 1); MFMA8(0, 2);                                     \
    __builtin_amdgcn_s_setprio(0);                                             \
    if (DO_STAGE) STAGE_B1(Q, (T) + 1);                                        \
    __builtin_amdgcn_s_setprio(1);                                             \
    MFMA8(1, 0); MFMA8(1, 1); MFMA8(1, 2);                                     \
    __builtin_amdgcn_s_setprio(0);                                             \
  }

    STAGE_A(0, 0, 0); STAGE_B0(0, 0); STAGE_A(0, 1, 0); STAGE_B1(0, 0);

    for (int t = 0; t < 254; t += 2) {
        GS8(0, 1, t,     VMCNT(3), VMCNT(3), true);
        GS8(1, 0, t + 1, VMCNT(3), VMCNT(3), true);
    }
    GS8(0, 1, 254, VMCNT(3), VMCNT(3), true);
    GS8(1, 0, 255, VMCNT(2), VMCNT(0), false);

    // epilogue: out = s2[n] * acc/127 + b2[n]
    const int l31 = lane & 31;
    const int rowb = 4 * (lane >> 5);
#pragma unroll
    for (int j = 0; j < 3; j++) {
        int n = NT * 192 + wN * 96 + j * 32 + l31;
        float sc = s2[n] * (1.0f / 127.0f), bb = b2[n];
#pragma unroll
        for (int i = 0; i < 2; i++) {
            int mbase = MT * 256 + wM * 64 + i * 32;
#pragma unroll
            for (int reg = 0; reg < 16; reg++) {
                int m = mbase + (reg & 3) + 8 * (reg >> 2) + rowb;
                out[(size_t)m * 3072 + n] = sc * (float)acc[i][j][reg] + bb;
            }
        }
    }
#undef RDA8
#undef RDB8
#undef MFMA8
#undef GS8
}

// ---------------------------------------------------------------------------
extern "C" void kernel_launch(void* const* d_in, const int* in_sizes, int n_in,
                              void* d_out, int out_size, void* d_ws, size_t ws_size,
                              hipStream_t stream) {
    const float* x  = (const float*)d_in[0];   // [4096,1024]
    const float* w1 = (const float*)d_in[1];   // [1024,16384]
    const float* s1 = (const float*)d_in[2];   // [16384]
    const float* b1 = (const float*)d_in[3];   // [16384]
    const float* w2 = (const float*)d_in[4];   // [16384,3072]
    const float* s2 = (const float*)d_in[5];   // [3072]
    const float* b2 = (const float*)d_in[6];   // [3072]
    const float* n1 = (const float*)d_in[7];   // [1024,16384]
    const float* n2 = (const float*)d_in[8];   // [16384,3072]
    const void* scale_p = d_in[9];             // scalar
    float* out = (float*)d_out;

    // workspace (MiB offsets): xq 8 @0 | w1q 32 @8 | hq-i8 64 @40 | w2q-i8 48 @104
    if (ws_size < (264ull << 20)) return;
    unsigned char* ws = (unsigned char*)d_ws;
    unsigned short* xq  = (unsigned short*)(ws);
    unsigned short* w1q = (unsigned short*)(ws + (8ull << 20));
    unsigned char*  hq  = (unsigned char*)(ws + (40ull << 20));
    unsigned char*  w2q = (unsigned char*)(ws + (104ull << 20));

    // fused pack/quant (one dispatch: w2-i8 | w1-bf16 | pack_x)
    prep_kernel<<<dim3(11264), 256, 0, stream>>>(
        x, xq, w1, n1, w1q, w2, n2, w2q, scale_p);

    // GEMM1 (bf16 core, i8 hq out)
    gemm1_256_kernel<<<dim3(16, 64), 512, 0, stream>>>(w1q, xq, hq, s1, b1);
    // GEMM2 (i8): 256x192 exact-fill
    gemm2_192_i8<<<dim3(16, 16), 512, 0, stream>>>(hq, w2q, out, s2, b2);
}